// Round 23
// baseline (281.185 us; speedup 1.0000x reference)
//
#include <hip/hip_runtime.h>
#include <hip/hip_fp16.h>

// Shapes (fixed by the reference setup_inputs)
#define NB 2
#define NH 16
#define NS 2048
#define ND 64

typedef __attribute__((ext_vector_type(8))) _Float16 half8;
typedef __attribute__((ext_vector_type(4))) _Float16 half4;
typedef __attribute__((ext_vector_type(4))) float float4v;
typedef __attribute__((ext_vector_type(2))) float float2v;

static constexpr int NE  = NB * NH * NS * ND;    // 4,194,304 elems per tensor
static constexpr int TPB = 512;                  // 8 waves

// LDS-only workgroup barrier (R14-verified): syncs LDS without vmcnt drain.
__device__ __forceinline__ void wg_barrier_lds() {
    asm volatile("s_waitcnt lgkmcnt(0)" ::: "memory");
    __builtin_amdgcn_s_barrier();
    __builtin_amdgcn_sched_barrier(0);
}
// Wave-local LDS RAW/WAR guard (own ds ops retired; no hoisting).
__device__ __forceinline__ void wave_lds_guard() {
    asm volatile("s_waitcnt lgkmcnt(0)" ::: "memory");
    __builtin_amdgcn_sched_barrier(0);
}

// ---------------------------------------------------------------------------
// Fused prep kernel (R15/R16-verified, unchanged).
// kr6 (per bh): [kt][oct=d/8][key%16][d%8] -> QK^T B-frag load 1024B contig.
// v4  (per bh): [kt][dblk=d/16][kq][d%16][key%4] -> PV A-frag load 512B contig.
// ---------------------------------------------------------------------------
static constexpr int ROPE_BLKS = (NE / 2) / 256;          // 8192
static constexpr int VT_BLKS   = NE / 256;                // 16384
static constexpr int MP_BLKS   = (NB * NS * NS) / 256;    // 32768

__global__ void prep_kernel(const float* __restrict__ q,
                            const float* __restrict__ k,
                            const float* __restrict__ v,
                            const int* __restrict__ mask,
                            _Float16* __restrict__ qr,
                            _Float16* __restrict__ kr6,
                            _Float16* __restrict__ v4,
                            unsigned int* __restrict__ mp) {
    int blk = blockIdx.x;
    if (blk < ROPE_BLKS) {
        int idx = blk * 256 + threadIdx.x;          // over NE/2
        int i   = idx & 31;
        int row = idx >> 5;
        int s   = row & (NS - 1);
        int bh  = row >> 11;

        float inv_freq = expf((float)i * -0.2878231366242710f);  // 10000^(-i/32)
        float ang = (float)s * inv_freq;
        float sn, cs;
        sincosf(ang, &sn, &cs);

        size_t base = (size_t)row * ND + 2 * i;
        float q0 = q[base], q1 = q[base + 1];
        float k0 = k[base], k1 = k[base + 1];
        qr[base]     = (_Float16)(q0 * cs - q1 * sn);
        qr[base + 1] = (_Float16)(q1 * cs + q0 * sn);

        int oct = i >> 2;
        int j0  = (2 * i) & 7;
        size_t t6 = ((size_t)(bh * 128 + (s >> 4)) * 8 + oct) * 128 + (s & 15) * 8 + j0;
        kr6[t6]     = (_Float16)(k0 * cs - k1 * sn);
        kr6[t6 + 1] = (_Float16)(k1 * cs + k0 * sn);
    } else if (blk < ROPE_BLKS + VT_BLKS) {
        int idx = (blk - ROPE_BLKS) * 256 + threadIdx.x;
        int j    = idx & 3;
        int lm   = (idx >> 2) & 15;
        int kq   = (idx >> 6) & 3;
        int dblk = (idx >> 8) & 3;
        int kt   = (idx >> 10) & 127;
        int bh   = idx >> 17;
        int key  = kt * 16 + kq * 4 + j;
        int d    = dblk * 16 + lm;
        v4[idx] = (_Float16)v[((size_t)bh * NS + key) * ND + d];
    } else {
        size_t idx = (size_t)(blk - ROPE_BLKS - VT_BLKS) * 256 + threadIdx.x;
        unsigned long long bal = __ballot(mask[idx] != 0);
        int l = threadIdx.x & 63;
        if (l == 0)       mp[idx >> 5] = (unsigned int)bal;
        else if (l == 32) mp[idx >> 5] = (unsigned int)(bal >> 32);
    }
}

// ---------------------------------------------------------------------------
// Attention kernel (R23): R19 dataflow with HALF-STRIP key staging for
// 3 WG/CU occupancy. Wave w owns keys [w*256,+256); key-tiles 0..7 are
// staged to a half-size wave-private LDS slice, key-tiles 8..15 stay in
// earr[8] registers. LDS 39.4 KB (was 72.3) and launch_bounds(512,6)
// (85-VGPR cap) -> 3 WG/CU = 24 waves: staggered WG phases overlap
// loads and stores; more waves hide phase-1 latency.
// Phase 2: two rounds of 512B single-segment nt row-stores (half rows),
// wave-local re-stage of earr between rounds (R18/R19 width curve:
// 512B ~ 1KB within a few us).
// DETERMINISM: no LDS atomics/init; unique-owner writes before barriers;
// fixed-order sums. Numerics: e rounds through fp16 as in R16/R19.
// ---------------------------------------------------------------------------
static constexpr int TPH    = 136;        // trans pitch in halfs (272 B)
static constexpr int WSLICE = 16 * TPH;   // halfs per wave slice (4352 B)

__global__ __launch_bounds__(TPB, 6)
void attn_reg_kernel(const _Float16* __restrict__ qr,
                     const _Float16* __restrict__ kr6,
                     const _Float16* __restrict__ v4,
                     const unsigned int* __restrict__ mp,
                     float* __restrict__ out,
                     float* __restrict__ score) {
    __shared__ unsigned int maskb[16 * 64];        // 4 KB
    __shared__ float        sums8[8][16];          // 512 B
    __shared__ _Float16     pool[8 * WSLICE];      // 34,816 B (trans, outb alias)

    // XCD-aware bijective swizzle: 4096 WGs -> contiguous 512 per XCD
    int wgid = (blockIdx.x & 7) * 512 + (blockIdx.x >> 3);
    int qt = wgid & 127;
    int bh = wgid >> 7;
    int b  = bh >> 4;
    int q0 = qt * 16;

    int tid = threadIdx.x;
    int w   = tid >> 6;
    int l   = tid & 63;
    int lm  = l & 15;
    int lp  = l >> 4;

    {
        const unsigned int* mrow = mp + ((size_t)b * NS + q0) * 64;
        for (int i = tid; i < 16 * 64; i += TPB) maskb[i] = mrow[i];
    }

    // Q B-fragment (col n = q = lm, k-slice d = lp*8+[0..7] (+32))
    const _Float16* qrow = qr + ((size_t)bh * NS + q0 + lm) * ND;
    half8 a0 = *(const half8*)(qrow + lp * 8);
    half8 a1 = *(const half8*)(qrow + 32 + lp * 8);
    const _Float16* k6 = kr6 + (size_t)bh * 128 * 1024;
    const _Float16* vb = v4 + (size_t)bh * 128 * 1024 + l * 4;
    _Float16* tw = pool + w * WSLICE;               // wave-private trans slice
    wg_barrier_lds();                      // maskb visible

    // ---- phase 1: fused {QK^T -> exp -> (stage | regs) | PV MFMA} + sums ----
    float4v ac0 = {0.f, 0.f, 0.f, 0.f};
    float4v ac1 = {0.f, 0.f, 0.f, 0.f};
    float4v ac2 = {0.f, 0.f, 0.f, 0.f};
    float4v ac3 = {0.f, 0.f, 0.f, 0.f};
    half4 earr[8];
    float ps = 0.0f;
#pragma unroll
    for (int t = 0; t < 16; ++t) {
        int kt = w * 16 + t;
        const _Float16* kp = k6 + (size_t)kt * 1024 + l * 8;
        half8 b0 = *(const half8*)(kp);          // 1024B contiguous wave-load
        half8 b1 = *(const half8*)(kp + 512);
        float4v acc = {0.f, 0.f, 0.f, 0.f};
        acc = __builtin_amdgcn_mfma_f32_16x16x32_f16(b0, a0, acc, 0, 0, 0);  // A=K rows
        acc = __builtin_amdgcn_mfma_f32_16x16x32_f16(b1, a1, acc, 0, 0, 0);  // B=Q rows
        // acc[r]: key = kt*16 + lp*4 + r, q = q0 + lm
        int keyb = kt * 16 + lp * 4;
        unsigned int mw = maskb[lm * 64 + (keyb >> 5)];
        int bit0 = keyb & 31;
        half4 ep;
#pragma unroll
        for (int r = 0; r < 4; ++r) {
            float ev = ((mw >> (bit0 + r)) & 1u) ? __expf(acc[r] * 0.125f) : 0.0f;
            ps += ev;
            ep[r] = (_Float16)ev;
        }
        if (t < 8) {
            // stage first half into wave-private trans (ds_write_b64)
            *(half4*)(tw + lm * TPH + t * 16 + lp * 4) = ep;
        } else {
            earr[t - 8] = ep;                // keep second half in regs
        }
        // PV for this key-subtile
        const _Float16* vp = vb + (size_t)kt * 1024;
        half4 af0 = *(const half4*)(vp);         // 512B contiguous wave-loads
        half4 af1 = *(const half4*)(vp + 256);
        half4 af2 = *(const half4*)(vp + 512);
        half4 af3 = *(const half4*)(vp + 768);
        __builtin_amdgcn_s_setprio(1);
        ac0 = __builtin_amdgcn_mfma_f32_16x16x16f16(af0, ep, ac0, 0, 0, 0);
        ac1 = __builtin_amdgcn_mfma_f32_16x16x16f16(af1, ep, ac1, 0, 0, 0);
        ac2 = __builtin_amdgcn_mfma_f32_16x16x16f16(af2, ep, ac2, 0, 0, 0);
        ac3 = __builtin_amdgcn_mfma_f32_16x16x16f16(af3, ep, ac3, 0, 0, 0);
        __builtin_amdgcn_s_setprio(0);
    }
    ps += __shfl_xor(ps, 16);
    ps += __shfl_xor(ps, 32);
    if (lp == 0) sums8[w][lm] = ps;        // plain store, unique slot
    wg_barrier_lds();                       // sums8 + own trans writes visible

    // ---- phase 2: two rounds of 512B single-segment nt row-stores ----
    {
        float s = 0.0f;
#pragma unroll
        for (int ww = 0; ww < 8; ++ww) s += sums8[ww][lm];   // fixed order
        float iv = (s > 0.0f) ? (1.0f / s) : 0.0f;           // iv for q-row = lm
        float* sbase = score + ((size_t)bh * NS + q0) * NS + w * 256;

        // round A: cols [0,128) of the wave strip, from trans
#pragma unroll
        for (int r = 0; r < 16; ++r) {
            float ivr = __shfl(iv, r);
            // lane l -> 2 halfs at col 2l (ds_read_b32)
            half res0 = tw[r * TPH + l * 2];
            half res1 = tw[r * TPH + l * 2 + 1];
            float2v f;
            f[0] = (float)(_Float16)res0 * ivr;
            f[1] = (float)(_Float16)res1 * ivr;
            __builtin_nontemporal_store(f, (float2v*)(sbase + (size_t)r * NS + l * 2));
        }
        // re-stage second half through the same slice (reads done)
        wave_lds_guard();
#pragma unroll
        for (int t = 0; t < 8; ++t)
            *(half4*)(tw + lm * TPH + t * 16 + lp * 4) = earr[t];
        wave_lds_guard();
        // round B: cols [128,256) of the wave strip
#pragma unroll
        for (int r = 0; r < 16; ++r) {
            float ivr = __shfl(iv, r);
            half res0 = tw[r * TPH + l * 2];
            half res1 = tw[r * TPH + l * 2 + 1];
            float2v f;
            f[0] = (float)(_Float16)res0 * ivr;
            f[1] = (float)(_Float16)res1 * ivr;
            __builtin_nontemporal_store(f, (float2v*)(sbase + (size_t)r * NS + 128 + l * 2));
        }
    }
    // trans slice dead; reuse for outb. Guard then per-wave plain writes.
    wave_lds_guard();
    {
        float* ow = (float*)tw + lm * 64 + lp * 4;   // 4KB of 4.35KB slice
#pragma unroll
        for (int r = 0; r < 4; ++r) {
            ow[ 0 + r] = ac0[r];
            ow[16 + r] = ac1[r];
            ow[32 + r] = ac2[r];
            ow[48 + r] = ac3[r];
        }
    }
    wg_barrier_lds();   // outb visible (score stores still in flight)

    // ---- phase 3: out = (sum of 8 wave slices) * invs (nt) ----
    {
        float* orow = out + ((size_t)bh * NS + q0) * ND;
        for (int i = tid; i < 16 * 64; i += TPB) {
            int r = i >> 6;
            float s = 0.0f;
#pragma unroll
            for (int ww = 0; ww < 8; ++ww) s += sums8[ww][r];  // fixed order
            float iv = (s > 0.0f) ? (1.0f / s) : 0.0f;
            float acc = 0.0f;
#pragma unroll
            for (int ww = 0; ww < 8; ++ww)
                acc += ((const float*)(pool + ww * WSLICE))[i];
            __builtin_nontemporal_store(acc * iv, &orow[i]);
        }
    }
}

// ---------------------------------------------------------------------------
extern "C" void kernel_launch(void* const* d_in, const int* in_sizes, int n_in,
                              void* d_out, int out_size, void* d_ws, size_t ws_size,
                              hipStream_t stream) {
    const float* q    = (const float*)d_in[0];
    const float* k    = (const float*)d_in[1];
    const float* v    = (const float*)d_in[2];
    const int*   mask = (const int*)d_in[3];

    float* out   = (float*)d_out;            // [B,H,S,D]
    float* score = out + (size_t)NE;         // [B,H,S,S]

    _Float16* qrw = (_Float16*)d_ws;
    _Float16* kr6 = qrw + NE;
    _Float16* v4w = kr6 + NE;
    unsigned int* mp = (unsigned int*)(v4w + NE);   // NB*NS*NS/32 words = 1 MB

    prep_kernel<<<dim3(ROPE_BLKS + VT_BLKS + MP_BLKS), dim3(256), 0, stream>>>(
        q, k, v, mask, qrw, kr6, v4w, mp);
    attn_reg_kernel<<<dim3(NB * NH * (NS / 16)), dim3(TPB), 0, stream>>>(
        qrw, kr6, v4w, mp, out, score);
}

// Round 24
// 171.817 us; speedup vs baseline: 1.6365x; 1.6365x over previous
//
#include <hip/hip_runtime.h>
#include <hip/hip_fp16.h>

// Shapes (fixed by the reference setup_inputs)
#define NB 2
#define NH 16
#define NS 2048
#define ND 64

typedef __attribute__((ext_vector_type(8))) _Float16 half8;
typedef __attribute__((ext_vector_type(4))) _Float16 half4;
typedef __attribute__((ext_vector_type(4))) float float4v;

static constexpr int NE = NB * NH * NS * ND;     // 4,194,304 elems per tensor
static constexpr int TPB = 512;                  // 8 waves

// LDS-only workgroup barrier (R14-verified, -45us vs __syncthreads):
// syncs LDS writes across waves WITHOUT the vmcnt(0) drain.
__device__ __forceinline__ void wg_barrier_lds() {
    asm volatile("s_waitcnt lgkmcnt(0)" ::: "memory");
    __builtin_amdgcn_s_barrier();
    __builtin_amdgcn_sched_barrier(0);
}

// ---------------------------------------------------------------------------
// Fused prep kernel (R15/R16-verified): three independent streams, ONE launch.
// kr6 (per bh): [kt][oct=d/8][key%16][d%8] -> QK^T B-frag load is 1024B contig.
// v4  (per bh): [kt][dblk=d/16][kq][d%16][key%4] -> PV A-frag load 512B contig.
// ---------------------------------------------------------------------------
static constexpr int ROPE_BLKS = (NE / 2) / 256;          // 8192
static constexpr int VT_BLKS   = NE / 256;                // 16384
static constexpr int MP_BLKS   = (NB * NS * NS) / 256;    // 32768

__global__ void prep_kernel(const float* __restrict__ q,
                            const float* __restrict__ k,
                            const float* __restrict__ v,
                            const int* __restrict__ mask,
                            _Float16* __restrict__ qr,
                            _Float16* __restrict__ kr6,
                            _Float16* __restrict__ v4,
                            unsigned int* __restrict__ mp) {
    int blk = blockIdx.x;
    if (blk < ROPE_BLKS) {
        int idx = blk * 256 + threadIdx.x;          // over NE/2
        int i   = idx & 31;        // freq index (d pair = 2i, 2i+1)
        int row = idx >> 5;        // (b*NH + h)*NS + s
        int s   = row & (NS - 1);
        int bh  = row >> 11;

        float inv_freq = expf((float)i * -0.2878231366242710f);  // 10000^(-i/32)
        float ang = (float)s * inv_freq;
        float sn, cs;
        sincosf(ang, &sn, &cs);

        size_t base = (size_t)row * ND + 2 * i;
        float q0 = q[base], q1 = q[base + 1];
        float k0 = k[base], k1 = k[base + 1];
        qr[base]     = (_Float16)(q0 * cs - q1 * sn);
        qr[base + 1] = (_Float16)(q1 * cs + q0 * sn);

        int oct = i >> 2;
        int j0  = (2 * i) & 7;
        size_t t6 = ((size_t)(bh * 128 + (s >> 4)) * 8 + oct) * 128 + (s & 15) * 8 + j0;
        kr6[t6]     = (_Float16)(k0 * cs - k1 * sn);
        kr6[t6 + 1] = (_Float16)(k1 * cs + k0 * sn);
    } else if (blk < ROPE_BLKS + VT_BLKS) {
        int idx = (blk - ROPE_BLKS) * 256 + threadIdx.x;   // linear v4 index
        int j    = idx & 3;            // key%4
        int lm   = (idx >> 2) & 15;    // d%16
        int kq   = (idx >> 6) & 3;     // (key%16)/4
        int dblk = (idx >> 8) & 3;
        int kt   = (idx >> 10) & 127;
        int bh   = idx >> 17;
        int key  = kt * 16 + kq * 4 + j;
        int d    = dblk * 16 + lm;
        v4[idx] = (_Float16)v[((size_t)bh * NS + key) * ND + d];
    } else {
        size_t idx = (size_t)(blk - ROPE_BLKS - VT_BLKS) * 256 + threadIdx.x;
        unsigned long long bal = __ballot(mask[idx] != 0);
        int l = threadIdx.x & 63;
        if (l == 0)       mp[idx >> 5] = (unsigned int)bal;
        else if (l == 32) mp[idx >> 5] = (unsigned int)(bal >> 32);
    }
}

// ---------------------------------------------------------------------------
// Attention kernel (R19, restored verbatim): 1KB single-segment nt score
// stores. Phase 1 per key-tile: {K-load, QK^T MFMA, mask+exp (+reg row-sum),
//   stage e fp16 -> wave-private LDS trans[16][TPH] (b64, 528B pitch:
//   breaks the 16-way bank conflict), V-load, PV MFMA}. earr eliminated.
// After sums barrier: readback row r (ds_read_b64, lane l -> cols 4l),
//   convert x iv (broadcast via __shfl(iv, r)), ONE fully-contiguous 1KB
//   nt store per row. outb ALIASES the dead trans slice (wave-private;
//   lgkmcnt+sched_barrier guard) -> LDS 70.5 KB, 2 WG/CU.
// DETERMINISM: no LDS atomics/init; unique-owner LDS writes before
// barrier; fixed-order final sums.
// ---------------------------------------------------------------------------
static constexpr int TPH    = 264;        // trans pitch in halfs (528 B)
static constexpr int WSLICE = 16 * TPH;   // halfs per wave slice (8448 B)

__global__ __launch_bounds__(TPB, 4)
void attn_reg_kernel(const _Float16* __restrict__ qr,
                     const _Float16* __restrict__ kr6,
                     const _Float16* __restrict__ v4,
                     const unsigned int* __restrict__ mp,
                     float* __restrict__ out,
                     float* __restrict__ score) {
    __shared__ unsigned int maskb[16 * 64];        // 4 KB
    __shared__ float        sums8[8][16];          // 512 B
    __shared__ _Float16     pool[8 * WSLICE];      // 67,584 B: trans, then outb alias

    // XCD-aware bijective swizzle: 4096 WGs -> contiguous 512 per XCD
    int wgid = (blockIdx.x & 7) * 512 + (blockIdx.x >> 3);
    int qt = wgid & 127;
    int bh = wgid >> 7;
    int b  = bh >> 4;
    int q0 = qt * 16;

    int tid = threadIdx.x;
    int w   = tid >> 6;
    int l   = tid & 63;
    int lm  = l & 15;
    int lp  = l >> 4;

    {
        const unsigned int* mrow = mp + ((size_t)b * NS + q0) * 64;
        for (int i = tid; i < 16 * 64; i += TPB) maskb[i] = mrow[i];
    }

    // Q B-fragment (col n = q = lm, k-slice d = lp*8+[0..7] (+32))
    const _Float16* qrow = qr + ((size_t)bh * NS + q0 + lm) * ND;
    half8 a0 = *(const half8*)(qrow + lp * 8);
    half8 a1 = *(const half8*)(qrow + 32 + lp * 8);
    const _Float16* k6 = kr6 + (size_t)bh * 128 * 1024;
    _Float16* tw = pool + w * WSLICE;               // wave-private trans slice
    wg_barrier_lds();                      // maskb visible

    // ---- phase 1: fused {QK^T -> exp -> stage fp16 | PV MFMA} + row sums ----
    float4v ac0 = {0.f, 0.f, 0.f, 0.f};
    float4v ac1 = {0.f, 0.f, 0.f, 0.f};
    float4v ac2 = {0.f, 0.f, 0.f, 0.f};
    float4v ac3 = {0.f, 0.f, 0.f, 0.f};
    const _Float16* vb = v4 + (size_t)bh * 128 * 1024 + l * 4;
    float ps = 0.0f;
#pragma unroll
    for (int t = 0; t < 16; ++t) {
        int kt = w * 16 + t;
        const _Float16* kp = k6 + (size_t)kt * 1024 + l * 8;
        half8 b0 = *(const half8*)(kp);          // 1024B contiguous wave-load
        half8 b1 = *(const half8*)(kp + 512);
        float4v acc = {0.f, 0.f, 0.f, 0.f};
        acc = __builtin_amdgcn_mfma_f32_16x16x32_f16(b0, a0, acc, 0, 0, 0);  // A=K rows
        acc = __builtin_amdgcn_mfma_f32_16x16x32_f16(b1, a1, acc, 0, 0, 0);  // B=Q rows
        // acc[r]: key = kt*16 + lp*4 + r, q = q0 + lm
        int keyb = kt * 16 + lp * 4;
        unsigned int mw = maskb[lm * 64 + (keyb >> 5)];
        int bit0 = keyb & 31;
        half4 ep;
#pragma unroll
        for (int r = 0; r < 4; ++r) {
            float ev = ((mw >> (bit0 + r)) & 1u) ? __expf(acc[r] * 0.125f) : 0.0f;
            ps += ev;
            ep[r] = (_Float16)ev;
        }
        // stage e fp16 into wave-private trans (ds_write_b64)
        *(half4*)(tw + lm * TPH + t * 16 + lp * 4) = ep;

        // PV for this key-subtile
        const _Float16* vp = vb + (size_t)kt * 1024;
        half4 af0 = *(const half4*)(vp);         // 512B contiguous wave-loads
        half4 af1 = *(const half4*)(vp + 256);
        half4 af2 = *(const half4*)(vp + 512);
        half4 af3 = *(const half4*)(vp + 768);
        __builtin_amdgcn_s_setprio(1);
        ac0 = __builtin_amdgcn_mfma_f32_16x16x16f16(af0, ep, ac0, 0, 0, 0);
        ac1 = __builtin_amdgcn_mfma_f32_16x16x16f16(af1, ep, ac1, 0, 0, 0);
        ac2 = __builtin_amdgcn_mfma_f32_16x16x16f16(af2, ep, ac2, 0, 0, 0);
        ac3 = __builtin_amdgcn_mfma_f32_16x16x16f16(af3, ep, ac3, 0, 0, 0);
        __builtin_amdgcn_s_setprio(0);
    }
    ps += __shfl_xor(ps, 16);
    ps += __shfl_xor(ps, 32);
    if (lp == 0) sums8[w][lm] = ps;        // plain store, unique slot
    wg_barrier_lds();                       // sums8 + own trans writes visible

    // ---- phase 2: per-row 1KB single-segment nt score stores ----
    {
        float s = 0.0f;
#pragma unroll
        for (int ww = 0; ww < 8; ++ww) s += sums8[ww][lm];   // fixed order
        float iv = (s > 0.0f) ? (1.0f / s) : 0.0f;           // iv for q-row = lm
        float* sbase = score + ((size_t)bh * NS + q0) * NS + w * 256;
#pragma unroll
        for (int r = 0; r < 16; ++r) {
            float ivr = __shfl(iv, r);       // row r's inverse (lane r broadcast)
            half4 hv = *(const half4*)(tw + r * TPH + l * 4);   // ds_read_b64
            float4v f;
            f[0] = (float)hv[0] * ivr;
            f[1] = (float)hv[1] * ivr;
            f[2] = (float)hv[2] * ivr;
            f[3] = (float)hv[3] * ivr;
            // 64 lanes x 16B = 1KB fully contiguous, single segment
            __builtin_nontemporal_store(f, (float4v*)(sbase + (size_t)r * NS + l * 4));
        }
    }
    // trans slice is dead; reuse it for outb. Guard: own ds_reads complete,
    // and forbid the compiler from hoisting the writes above the reads.
    asm volatile("s_waitcnt lgkmcnt(0)" ::: "memory");
    __builtin_amdgcn_sched_barrier(0);

    // per-wave outb slices (C-frag: q = lm cols, d_local = lp*4 + reg)
    {
        float* ow = (float*)tw + lm * 64 + lp * 4;   // 4KB used of 8.4KB slice
#pragma unroll
        for (int r = 0; r < 4; ++r) {
            ow[ 0 + r] = ac0[r];
            ow[16 + r] = ac1[r];
            ow[32 + r] = ac2[r];
            ow[48 + r] = ac3[r];
        }
    }
    wg_barrier_lds();   // outb visible (score stores still in flight)

    // ---- phase 3: out = (sum of 8 wave slices) * invs (nt) ----
    {
        float* orow = out + ((size_t)bh * NS + q0) * ND;
        for (int i = tid; i < 16 * 64; i += TPB) {
            int r = i >> 6;
            float s = 0.0f;
#pragma unroll
            for (int ww = 0; ww < 8; ++ww) s += sums8[ww][r];  // fixed order
            float iv = (s > 0.0f) ? (1.0f / s) : 0.0f;
            float acc = 0.0f;
#pragma unroll
            for (int ww = 0; ww < 8; ++ww)
                acc += ((const float*)(pool + ww * WSLICE))[i];
            __builtin_nontemporal_store(acc * iv, &orow[i]);
        }
    }
}

// ---------------------------------------------------------------------------
extern "C" void kernel_launch(void* const* d_in, const int* in_sizes, int n_in,
                              void* d_out, int out_size, void* d_ws, size_t ws_size,
                              hipStream_t stream) {
    const float* q    = (const float*)d_in[0];
    const float* k    = (const float*)d_in[1];
    const float* v    = (const float*)d_in[2];
    const int*   mask = (const int*)d_in[3];

    float* out   = (float*)d_out;            // [B,H,S,D]
    float* score = out + (size_t)NE;         // [B,H,S,S]

    _Float16* qrw = (_Float16*)d_ws;
    _Float16* kr6 = qrw + NE;
    _Float16* v4w = kr6 + NE;
    unsigned int* mp = (unsigned int*)(v4w + NE);   // NB*NS*NS/32 words = 1 MB

    prep_kernel<<<dim3(ROPE_BLKS + VT_BLKS + MP_BLKS), dim3(256), 0, stream>>>(
        q, k, v, mask, qrw, kr6, v4w, mp);
    attn_reg_kernel<<<dim3(NB * NH * (NS / 16)), dim3(TPB), 0, stream>>>(
        qrw, kr6, v4w, mp, out, score);
}